// Round 14
// baseline (174.735 us; speedup 1.0000x reference)
//
#include <hip/hip_runtime.h>
#include <hip/hip_bf16.h>

// GradientLayer: 4->128->128->128->5 tanh MLP; per-sample Jacobian (5x4) and
// Hessians of outputs 0 and 4, combined into 17 outputs.
// Round 14 (from validated round 13):
//  - t4-loop "#pragma unroll 2": only 2 f32x16 accumulators live at once
//    (was 4 with full unroll = 64 regs) -> peak live ~94 regs.
//  - __launch_bounds__(256,5): 5 waves/SIMD (cap <=102 regs). R11 showed the
//    cap alone spills; R12 showed chain-ILP beyond 2 is worthless. This pairs
//    the cap WITH the pressure reduction.
//  - Everything else identical to round 13 (permlane32_swap broadcasts).

namespace {

constexpr int HID = 128;

using bf16x8 = __attribute__((ext_vector_type(8))) short;
using f32x16 = __attribute__((ext_vector_type(16))) float;
typedef unsigned       __attribute__((may_alias)) u32a;
typedef unsigned short __attribute__((may_alias)) u16a;

#define LDS_FENCE() asm volatile("" ::: "memory")

struct OSpec {
    int base, mul, off;
    int a0, a1, a2, m;
    int b0, b1, b2, m2;
    float s1, s2;
};

// comb[] indexed by ROW (permuted): value at row*5+k.
// Row map sigma(v): {0:0,1:1,2:5,3:2,4:6,5:3,6:7,7:8,8:12,9:9,10:13,11:10,
// 12:14,13:11,14:15}. Indices below = sigma(v)*5+k of the validated table.
// comb[80]=0, comb[81]=1.
__constant__ OSpec g_ospec[38] = {
    {0,1,0,   0,80,80,81, 80,80,80,81, 1.f,0.f},   // n
    {1,1,0,   5,80,80,81, 80,80,80,81, 1.f,0.f},   // n_t
    {2,3,0,  25,80,80,81, 80,80,80,81, 1.f,0.f},   // n_grd (v2->row5)
    {2,3,1,  10,80,80,81, 80,80,80,81, 1.f,0.f},   //       (v3->row2)
    {2,3,2,  30,80,80,81, 80,80,80,81, 1.f,0.f},   //       (v4->row6)
    {5,3,0,   1,80,80, 0, 80,80,80,81, 1.f,0.f},   // j = n*v
    {5,3,1,   2,80,80, 0, 80,80,80,81, 1.f,0.f},
    {5,3,2,   3,80,80, 0, 80,80,80,81, 1.f,0.f},
    {8,3,0,  25,10,30, 1, 26,11,31, 0, 1.f,1.f},   // j_div
    {8,3,1,  25,10,30, 2, 27,12,32, 0, 1.f,1.f},
    {8,3,2,  25,10,30, 3, 28,13,33, 0, 1.f,1.f},
    {11,1,0,  4,80,80,81, 80,80,80,81, 1.f,0.f},   // Fi
    {12,3,0, 29,80,80,81, 80,80,80,81, 1.f,0.f},   // Fi_grd
    {12,3,1, 14,80,80,81, 80,80,80,81, 1.f,0.f},
    {12,3,2, 34,80,80,81, 80,80,80,81, 1.f,0.f},
    {15,4,0, 39,44,64,81, 80,80,80,81, 1.f,0.f},   // Fi_lap (HFi p=1,2,3)
    {15,4,1, 49,69,54,81, 80,80,80,81, 1.f,0.f},   //        (p=4,5,6)
    {15,4,2, 69,74,59,81, 80,80,80,81, 1.f,0.f},   //        (p=5,7,8)
    {15,4,3, 54,59,79,81, 80,80,80,81, 1.f,0.f},   //        (p=6,8,9)
    {19,3,0,  1,80,80,81, 80,80,80,81, 1.f,0.f},   // v
    {19,3,1,  2,80,80,81, 80,80,80,81, 1.f,0.f},
    {19,3,2,  3,80,80,81, 80,80,80,81, 1.f,0.f},
    {22,1,0,  5,80,80,81, 80,80,80,81, 1.f,0.f},   // v_t
    {23,3,0,  1,80,80,25, 80,80,80,81, 1.f,0.f},   // v_adv
    {23,3,1,  2,80,80,10, 80,80,80,81, 1.f,0.f},
    {23,3,2,  3,80,80,30, 80,80,80,81, 1.f,0.f},
    {26,1,0, 35,65,55,81, 80,80,80,81, 1.f,0.f},   // v_lap (Hn p=1,5,8)
    {27,3,0, 45,65,50,81, 80,80,80,81, 1.f,0.f},   // v_div_grd (p=4,5,6)
    {27,3,1, 65,70,55,81, 80,80,80,81, 1.f,0.f},   //           (p=5,7,8)
    {27,3,2, 50,55,75,81, 80,80,80,81, 1.f,0.f},   //           (p=6,8,9)
    {30,1,0,  0,80,80,81, 80,80,80,81, 2.f,0.f},   // ro = 2n
    {31,1,0,  5,80,80,81, 80,80,80,81, 2.f,0.f},   // ro_t
    {32,3,0, 25,80,80,81, 80,80,80,81, 2.f,0.f},   // ro_grd
    {32,3,1, 10,80,80,81, 80,80,80,81, 2.f,0.f},
    {32,3,2, 30,80,80,81, 80,80,80,81, 2.f,0.f},
    {35,3,0, 25,10,30, 1, 26,11,31, 0, 2.f,2.f},   // rov_div
    {35,3,1, 25,10,30, 2, 27,12,32, 0, 2.f,2.f},
    {35,3,2, 25,10,30, 3, 28,13,33, 0, 2.f,2.f},
};

__device__ __forceinline__ unsigned short f2bf(float f) {
    union { float f; unsigned u; } v; v.f = f;
    unsigned r = v.u + 0x7FFFu + ((v.u >> 16) & 1u);   // RNE (pack kernel only)
    return (unsigned short)(r >> 16);
}
__device__ __forceinline__ unsigned pk_bf16(float lo, float hi) {
    __bf16 l = (__bf16)lo;
    __bf16 h = (__bf16)hi;
    unsigned short ul, uh;
    __builtin_memcpy(&ul, &l, 2);
    __builtin_memcpy(&uh, &h, 2);
    return (unsigned)ul | ((unsigned)uh << 16);
}
__device__ __forceinline__ unsigned short bf1(float x) {
    __bf16 b = (__bf16)x;
    unsigned short u; __builtin_memcpy(&u, &b, 2); return u;
}
__device__ __forceinline__ float tanh_fast(float z) {
    float e = __builtin_amdgcn_exp2f(z * 2.8853900817779268f);
    return 1.0f - 2.0f * __builtin_amdgcn_rcpf(e + 1.0f);
}
// value of x from partner lane (lane ^ 32), via VALU permlane (no LDS).
__device__ __forceinline__ float swap_half(float x, bool hi_) {
    float a = x, b = x;
    asm volatile("v_permlane32_swap_b32 %0, %1" : "+v"(a), "+v"(b));
    return hi_ ? a : b;
}
// swizzled byte offset inside a per-sample [16][128] bf16 A-buffer
__device__ __forceinline__ int swz(int row, int byte_in_row) {
    return (row * 256 + byte_in_row) ^ ((row & 7) << 4);
}

// ---- pack W1/W2 (+ W3 padded to 32 cols) into 32x32x16 B-fragments ---------
__global__ void pack_w_kernel(const float* __restrict__ W1,
                              const float* __restrict__ W2,
                              const float* __restrict__ W3,
                              unsigned short* __restrict__ wsB) {
    int t = blockIdx.x * 256 + threadIdx.x;        // 0..36863
    if (t < 32768) {
        int reg   = t & 7;
        int lane  = (t >> 3) & 63;
        int tile  = (t >> 9) & 3;
        int kt    = (t >> 11) & 7;
        int layer = (t >> 14) & 1;
        int k = kt * 16 + ((lane >> 5) & 1) * 8 + reg;
        int n = tile * 32 + (lane & 31);
        const float* W = layer ? W2 : W1;
        wsB[t] = f2bf(W[k * HID + n]);
    } else if (t < 36864) {
        int tt = t - 32768;
        int reg  = tt & 7;
        int lane = (tt >> 3) & 63;
        int kt   = (tt >> 9) & 7;
        int k = kt * 16 + ((lane >> 5) & 1) * 8 + reg;
        int n = lane & 31;
        wsB[t] = (n < 5) ? f2bf(W3[k * 5 + n]) : (unsigned short)0;
    }
}

__global__ __launch_bounds__(256, 5) void mlp_pde_kernel(
    const float* __restrict__ x,
    const float* __restrict__ W0, const float* __restrict__ b0,
    const float* __restrict__ b1, const float* __restrict__ b2,
    const float* __restrict__ b3,
    const unsigned short* __restrict__ wsB,
    float* __restrict__ out, int nb)
{
    constexpr int PD[10] = {0,0,0,0,1,1,1,2,2,3};
    constexpr int PE[10] = {0,1,2,3,1,2,3,2,3,3};
    constexpr int ROWMAP[15] = {0,1,5,2,6,3,7,8,12,9,13,10,14,11,15}; // v->row
    constexpr int RB[8] = {0,1,2,3,8,9,10,11};     // reg -> base row (hi=0)

    __shared__ float lds[4][2048];                 // 8192 B per wave
    const int wave = threadIdx.x >> 6;
    const int lane = threadIdx.x & 63;
    float* wbase = lds[wave];
    char* abufA = (char*)wbase;                    // [16][128] bf16, swizzled
    char* abufB = (char*)wbase + 4096;
    float* combA = wbase;                          // overlap (dead after tfrag)
    float* combB = wbase + 82;
    int bA = blockIdx.x * 8 + wave * 2;
    int bB = bA + 1;
    if (bA >= nb) bA = nb - 1;
    if (bB >= nb) bB = nb - 1;

    // ---------------- layer 0 (4 -> 128), fp32, lane owns cols 2l,2l+1 ------
    {
        const int j0 = lane * 2;
        float w0d[4][2];
        #pragma unroll
        for (int d = 0; d < 4; ++d) {
            float2 w = *reinterpret_cast<const float2*>(W0 + d * HID + j0);
            w0d[d][0] = w.x; w0d[d][1] = w.y;
        }
        const float2 bb0 = *reinterpret_cast<const float2*>(b0 + j0);
        const float4 xvA = *reinterpret_cast<const float4*>(x + 4 * bA);
        const float4 xvB = *reinterpret_cast<const float4*>(x + 4 * bB);
        #pragma unroll
        for (int s = 0; s < 2; ++s) {
            const float4 xv = s ? xvB : xvA;
            char* abuf = s ? abufB : abufA;
            float val[15][2];
            #pragma unroll
            for (int jj = 0; jj < 2; ++jj) {
                float z = ((jj == 0) ? bb0.x : bb0.y)
                        + xv.x * w0d[0][jj] + xv.y * w0d[1][jj]
                        + xv.z * w0d[2][jj] + xv.w * w0d[3][jj];
                float h = tanh_fast(z);
                float sd = 1.f - h * h;
                val[0][jj] = h;
                #pragma unroll
                for (int d = 0; d < 4; ++d) val[1 + d][jj] = sd * w0d[d][jj];
                #pragma unroll
                for (int p = 0; p < 10; ++p)
                    val[5 + p][jj] = -2.f * h * sd * w0d[PD[p]][jj] * w0d[PE[p]][jj];
            }
            #pragma unroll
            for (int v = 0; v < 15; ++v)
                *reinterpret_cast<u32a*>(abuf + swz(ROWMAP[v], j0 * 2)) =
                    pk_bf16(val[v][0], val[v][1]);
            *reinterpret_cast<u32a*>(abuf + swz(4, j0 * 2)) = 0u;   // pad row
        }
    }
    LDS_FENCE();   // layer-0 stores -> afrag reads

    // ---------------- layers 1,2 via 32x32x16 MFMA (stacked samples) --------
    const int col  = lane & 31;                    // output column in tile
    const int hi   = lane >> 5;                    // lane half
    const int arow = lane & 15;                    // A-row within sample
    char* abufM = (char*)wbase + ((lane >> 4) & 1) * 4096;  // m>=16 -> sample B

    #pragma unroll 1
    for (int layer = 0; layer < 2; ++layer) {
        // A fragments: lane holds A[m=lane&31][k = kt*16 + hi*8 + 0..7]
        bf16x8 af[8];
        #pragma unroll
        for (int kt = 0; kt < 8; ++kt)
            af[kt] = *reinterpret_cast<const bf16x8*>(
                abufM + swz(arow, kt * 32 + hi * 16));
        LDS_FENCE();   // afrag reads -> recomb stores (WAR)
        const float* bias = layer ? b2 : b1;
        float bv[4];
        #pragma unroll
        for (int t4 = 0; t4 < 4; ++t4) bv[t4] = bias[t4 * 32 + col];

        #pragma unroll 2
        for (int t4 = 0; t4 < 4; ++t4) {
            f32x16 acc = {0.f,0.f,0.f,0.f,0.f,0.f,0.f,0.f,
                          0.f,0.f,0.f,0.f,0.f,0.f,0.f,0.f};
            #pragma unroll
            for (int kt = 0; kt < 8; ++kt) {
                bf16x8 bfrag = *reinterpret_cast<const bf16x8*>(
                    wsB + ((size_t)(((layer * 8 + kt) * 4) + t4) * 512 + lane * 8));
                acc = __builtin_amdgcn_mfma_f32_32x32x16_bf16(af[kt], bfrag, acc, 0, 0, 0);
            }
            const bool H = (hi != 0);
            // partner-half values via VALU permlane32_swap (no LDS round-trip)
            float swA0 = swap_half(acc[0],  H);
            float swA1 = swap_half(acc[1],  H);
            float swA2 = swap_half(acc[2],  H);
            float swB0 = swap_half(acc[8],  H);
            float swB1 = swap_half(acc[9],  H);
            float swB2 = swap_half(acc[10], H);
            float zA  = H ? swA0   : acc[0];
            float uA0 = H ? swA1   : acc[1];
            float uA1 = H ? acc[1] : swA1;
            float uA2 = H ? swA2   : acc[2];
            float uA3 = H ? acc[2] : swA2;
            float zB  = H ? swB0   : acc[8];
            float uB0 = H ? swB1   : acc[9];
            float uB1 = H ? acc[9] : swB1;
            float uB2 = H ? swB2   : acc[10];
            float uB3 = H ? acc[10] : swB2;
            float hA = tanh_fast(zA + bv[t4]);
            float sA = 1.f - hA * hA;  float cA = -2.f * hA * sA;
            float hB = tanh_fast(zB + bv[t4]);
            float sB = 1.f - hB * hB;  float cB = -2.f * hB * sB;

            float nvA[8], nvB[8];
            nvA[0] = H ? 0.f : hA;                              // rows 0/4: v0|pad
            nvA[1] = sA * (H ? uA1 : uA0);                      // rows 1/5: v1|v2
            nvA[2] = sA * (H ? uA3 : uA2);                      // rows 2/6: v3|v4
            nvA[3] = fmaf(cA * uA0, H ? uA1 : uA0, sA * acc[3]);    // v5|v6
            nvA[4] = fmaf(cA * uA0, H ? uA3 : uA2, sA * acc[4]);    // v7|v8
            nvA[5] = fmaf(cA * uA1, H ? uA2 : uA1, sA * acc[5]);    // v9|v10
            nvA[6] = fmaf(cA * (H ? uA2 : uA1), H ? uA2 : uA3, sA * acc[6]); // v11|v12
            nvA[7] = fmaf(cA * (H ? uA3 : uA2), uA3, sA * acc[7]);  // v13|v14
            nvB[0] = H ? 0.f : hB;
            nvB[1] = sB * (H ? uB1 : uB0);
            nvB[2] = sB * (H ? uB3 : uB2);
            nvB[3] = fmaf(cB * uB0, H ? uB1 : uB0, sB * acc[11]);
            nvB[4] = fmaf(cB * uB0, H ? uB3 : uB2, sB * acc[12]);
            nvB[5] = fmaf(cB * uB1, H ? uB2 : uB1, sB * acc[13]);
            nvB[6] = fmaf(cB * (H ? uB2 : uB1), H ? uB2 : uB3, sB * acc[14]);
            nvB[7] = fmaf(cB * (H ? uB3 : uB2), uB3, sB * acc[15]);

            const int cb = (t4 * 32 + col) * 2;
            #pragma unroll
            for (int q = 0; q < 8; ++q) {
                int rowq = RB[q] + 4 * hi;
                *reinterpret_cast<u16a*>(abufA + swz(rowq, cb)) = bf1(nvA[q]);
                *reinterpret_cast<u16a*>(abufB + swz(rowq, cb)) = bf1(nvB[q]);
            }
        }
        LDS_FENCE();   // recomb stores -> next-layer / epilogue reads
    }

    // ---------------- epilogue: stacked T @ W3pad(128x32) via MFMA ----------
    bf16x8 tf[8];
    #pragma unroll
    for (int kt = 0; kt < 8; ++kt)
        tf[kt] = *reinterpret_cast<const bf16x8*>(
            abufM + swz(arow, kt * 32 + hi * 16));
    LDS_FENCE();   // tfrag reads -> comb stores (comb overlaps abufA)

    f32x16 fa = {0.f,0.f,0.f,0.f,0.f,0.f,0.f,0.f,
                 0.f,0.f,0.f,0.f,0.f,0.f,0.f,0.f};
    #pragma unroll
    for (int kt = 0; kt < 8; ++kt) {
        bf16x8 w3f = *reinterpret_cast<const bf16x8*>(
            wsB + 32768 + (size_t)(kt * 512 + lane * 8));
        fa = __builtin_amdgcn_mfma_f32_32x32x16_bf16(tf[kt], w3f, fa, 0, 0, 0);
    }

    if (col < 5) {
        float badd = (hi != 0) ? 0.f : b3[col];
        #pragma unroll
        for (int q = 0; q < 8; ++q) {
            int rowq = RB[q] + 4 * hi;
            float tA = fa[q];
            float tB = fa[q + 8];
            if (q == 0) { tA += badd; tB += badd; }
            combA[rowq * 5 + col] = tA;            // comb indexed by permuted row
            combB[rowq * 5 + col] = tB;
        }
    }
    if (lane == 63) { combA[80] = 0.f; combA[81] = 1.f; combB[80] = 0.f; combB[81] = 1.f; }
    LDS_FENCE();   // comb stores -> table reads

    // ---------------- table-driven writer: 38 outputs per sample ------------
    if (lane < 38) {
        OSpec sp = g_ospec[lane];
        float a1v = (combA[sp.a0] + combA[sp.a1] + combA[sp.a2]) * combA[sp.m] * sp.s1;
        float a2v = (combA[sp.b0] + combA[sp.b1] + combA[sp.b2]) * combA[sp.m2] * sp.s2;
        out[sp.base * nb + bA * sp.mul + sp.off] = a1v + a2v;
        float c1v = (combB[sp.a0] + combB[sp.a1] + combB[sp.a2]) * combB[sp.m] * sp.s1;
        float c2v = (combB[sp.b0] + combB[sp.b1] + combB[sp.b2]) * combB[sp.m2] * sp.s2;
        out[sp.base * nb + bB * sp.mul + sp.off] = c1v + c2v;
    }
}

} // namespace

extern "C" void kernel_launch(void* const* d_in, const int* in_sizes, int n_in,
                              void* d_out, int out_size, void* d_ws, size_t ws_size,
                              hipStream_t stream) {
    const float* x  = (const float*)d_in[0];
    const float* W0 = (const float*)d_in[1];
    const float* b0 = (const float*)d_in[2];
    const float* W1 = (const float*)d_in[3];
    const float* b1 = (const float*)d_in[4];
    const float* W2 = (const float*)d_in[5];
    const float* b2 = (const float*)d_in[6];
    const float* W3 = (const float*)d_in[7];
    const float* b3 = (const float*)d_in[8];
    float* out = (float*)d_out;
    unsigned short* wsB = (unsigned short*)d_ws;   // ~72 KB used

    const int nb = in_sizes[0] / 4;                // 32768
    pack_w_kernel<<<144, 256, 0, stream>>>(W1, W2, W3, wsB);
    const int blocks = (nb + 7) / 8;               // 8 samples (4 waves x 2) per block
    mlp_pde_kernel<<<blocks, 256, 0, stream>>>(x, W0, b0, b1, b2, b3, wsB, out, nb);
}

// Round 15
// 81.727 us; speedup vs baseline: 2.1380x; 2.1380x over previous
//
#include <hip/hip_runtime.h>
#include <hip/hip_bf16.h>

// GradientLayer: 4->128->128->128->5 tanh MLP; per-sample Jacobian (5x4) and
// Hessians of outputs 0 and 4, combined into 17 outputs.
// Round 15 (from validated round 13):
//  - #pragma unroll 2 on the t4-loop, KEEPING __launch_bounds__(256,4).
//    Diagnosis: measured 38% occupancy == exactly 3 waves/SIMD; full unroll's
//    4 live f32x16 accumulators push the unified VGPR+AGPR allocation to
//    ~160 regs (floor(512/160)=3). unroll-2 halves live accumulators ->
//    ~120-126 regs <= 128 -> 4 waves/SIMD (+33% TLP) without the <=102-reg
//    spill cliff that killed R11/R14.
//  - Everything else identical to round 13 (permlane32_swap broadcasts).

namespace {

constexpr int HID = 128;

using bf16x8 = __attribute__((ext_vector_type(8))) short;
using f32x16 = __attribute__((ext_vector_type(16))) float;
typedef unsigned       __attribute__((may_alias)) u32a;
typedef unsigned short __attribute__((may_alias)) u16a;

#define LDS_FENCE() asm volatile("" ::: "memory")

struct OSpec {
    int base, mul, off;
    int a0, a1, a2, m;
    int b0, b1, b2, m2;
    float s1, s2;
};

// comb[] indexed by ROW (permuted): value at row*5+k.
// Row map sigma(v): {0:0,1:1,2:5,3:2,4:6,5:3,6:7,7:8,8:12,9:9,10:13,11:10,
// 12:14,13:11,14:15}. Indices below = sigma(v)*5+k of the validated table.
// comb[80]=0, comb[81]=1.
__constant__ OSpec g_ospec[38] = {
    {0,1,0,   0,80,80,81, 80,80,80,81, 1.f,0.f},   // n
    {1,1,0,   5,80,80,81, 80,80,80,81, 1.f,0.f},   // n_t
    {2,3,0,  25,80,80,81, 80,80,80,81, 1.f,0.f},   // n_grd (v2->row5)
    {2,3,1,  10,80,80,81, 80,80,80,81, 1.f,0.f},   //       (v3->row2)
    {2,3,2,  30,80,80,81, 80,80,80,81, 1.f,0.f},   //       (v4->row6)
    {5,3,0,   1,80,80, 0, 80,80,80,81, 1.f,0.f},   // j = n*v
    {5,3,1,   2,80,80, 0, 80,80,80,81, 1.f,0.f},
    {5,3,2,   3,80,80, 0, 80,80,80,81, 1.f,0.f},
    {8,3,0,  25,10,30, 1, 26,11,31, 0, 1.f,1.f},   // j_div
    {8,3,1,  25,10,30, 2, 27,12,32, 0, 1.f,1.f},
    {8,3,2,  25,10,30, 3, 28,13,33, 0, 1.f,1.f},
    {11,1,0,  4,80,80,81, 80,80,80,81, 1.f,0.f},   // Fi
    {12,3,0, 29,80,80,81, 80,80,80,81, 1.f,0.f},   // Fi_grd
    {12,3,1, 14,80,80,81, 80,80,80,81, 1.f,0.f},
    {12,3,2, 34,80,80,81, 80,80,80,81, 1.f,0.f},
    {15,4,0, 39,44,64,81, 80,80,80,81, 1.f,0.f},   // Fi_lap (HFi p=1,2,3)
    {15,4,1, 49,69,54,81, 80,80,80,81, 1.f,0.f},   //        (p=4,5,6)
    {15,4,2, 69,74,59,81, 80,80,80,81, 1.f,0.f},   //        (p=5,7,8)
    {15,4,3, 54,59,79,81, 80,80,80,81, 1.f,0.f},   //        (p=6,8,9)
    {19,3,0,  1,80,80,81, 80,80,80,81, 1.f,0.f},   // v
    {19,3,1,  2,80,80,81, 80,80,80,81, 1.f,0.f},
    {19,3,2,  3,80,80,81, 80,80,80,81, 1.f,0.f},
    {22,1,0,  5,80,80,81, 80,80,80,81, 1.f,0.f},   // v_t
    {23,3,0,  1,80,80,25, 80,80,80,81, 1.f,0.f},   // v_adv
    {23,3,1,  2,80,80,10, 80,80,80,81, 1.f,0.f},
    {23,3,2,  3,80,80,30, 80,80,80,81, 1.f,0.f},
    {26,1,0, 35,65,55,81, 80,80,80,81, 1.f,0.f},   // v_lap (Hn p=1,5,8)
    {27,3,0, 45,65,50,81, 80,80,80,81, 1.f,0.f},   // v_div_grd (p=4,5,6)
    {27,3,1, 65,70,55,81, 80,80,80,81, 1.f,0.f},   //           (p=5,7,8)
    {27,3,2, 50,55,75,81, 80,80,80,81, 1.f,0.f},   //           (p=6,8,9)
    {30,1,0,  0,80,80,81, 80,80,80,81, 2.f,0.f},   // ro = 2n
    {31,1,0,  5,80,80,81, 80,80,80,81, 2.f,0.f},   // ro_t
    {32,3,0, 25,80,80,81, 80,80,80,81, 2.f,0.f},   // ro_grd
    {32,3,1, 10,80,80,81, 80,80,80,81, 2.f,0.f},
    {32,3,2, 30,80,80,81, 80,80,80,81, 2.f,0.f},
    {35,3,0, 25,10,30, 1, 26,11,31, 0, 2.f,2.f},   // rov_div
    {35,3,1, 25,10,30, 2, 27,12,32, 0, 2.f,2.f},
    {35,3,2, 25,10,30, 3, 28,13,33, 0, 2.f,2.f},
};

__device__ __forceinline__ unsigned short f2bf(float f) {
    union { float f; unsigned u; } v; v.f = f;
    unsigned r = v.u + 0x7FFFu + ((v.u >> 16) & 1u);   // RNE (pack kernel only)
    return (unsigned short)(r >> 16);
}
__device__ __forceinline__ unsigned pk_bf16(float lo, float hi) {
    __bf16 l = (__bf16)lo;
    __bf16 h = (__bf16)hi;
    unsigned short ul, uh;
    __builtin_memcpy(&ul, &l, 2);
    __builtin_memcpy(&uh, &h, 2);
    return (unsigned)ul | ((unsigned)uh << 16);
}
__device__ __forceinline__ unsigned short bf1(float x) {
    __bf16 b = (__bf16)x;
    unsigned short u; __builtin_memcpy(&u, &b, 2); return u;
}
__device__ __forceinline__ float tanh_fast(float z) {
    float e = __builtin_amdgcn_exp2f(z * 2.8853900817779268f);
    return 1.0f - 2.0f * __builtin_amdgcn_rcpf(e + 1.0f);
}
// value of x from partner lane (lane ^ 32), via VALU permlane (no LDS).
__device__ __forceinline__ float swap_half(float x, bool hi_) {
    float a = x, b = x;
    asm volatile("v_permlane32_swap_b32 %0, %1" : "+v"(a), "+v"(b));
    return hi_ ? a : b;
}
// swizzled byte offset inside a per-sample [16][128] bf16 A-buffer
__device__ __forceinline__ int swz(int row, int byte_in_row) {
    return (row * 256 + byte_in_row) ^ ((row & 7) << 4);
}

// ---- pack W1/W2 (+ W3 padded to 32 cols) into 32x32x16 B-fragments ---------
__global__ void pack_w_kernel(const float* __restrict__ W1,
                              const float* __restrict__ W2,
                              const float* __restrict__ W3,
                              unsigned short* __restrict__ wsB) {
    int t = blockIdx.x * 256 + threadIdx.x;        // 0..36863
    if (t < 32768) {
        int reg   = t & 7;
        int lane  = (t >> 3) & 63;
        int tile  = (t >> 9) & 3;
        int kt    = (t >> 11) & 7;
        int layer = (t >> 14) & 1;
        int k = kt * 16 + ((lane >> 5) & 1) * 8 + reg;
        int n = tile * 32 + (lane & 31);
        const float* W = layer ? W2 : W1;
        wsB[t] = f2bf(W[k * HID + n]);
    } else if (t < 36864) {
        int tt = t - 32768;
        int reg  = tt & 7;
        int lane = (tt >> 3) & 63;
        int kt   = (tt >> 9) & 7;
        int k = kt * 16 + ((lane >> 5) & 1) * 8 + reg;
        int n = lane & 31;
        wsB[t] = (n < 5) ? f2bf(W3[k * 5 + n]) : (unsigned short)0;
    }
}

__global__ __launch_bounds__(256, 4) void mlp_pde_kernel(
    const float* __restrict__ x,
    const float* __restrict__ W0, const float* __restrict__ b0,
    const float* __restrict__ b1, const float* __restrict__ b2,
    const float* __restrict__ b3,
    const unsigned short* __restrict__ wsB,
    float* __restrict__ out, int nb)
{
    constexpr int PD[10] = {0,0,0,0,1,1,1,2,2,3};
    constexpr int PE[10] = {0,1,2,3,1,2,3,2,3,3};
    constexpr int ROWMAP[15] = {0,1,5,2,6,3,7,8,12,9,13,10,14,11,15}; // v->row
    constexpr int RB[8] = {0,1,2,3,8,9,10,11};     // reg -> base row (hi=0)

    __shared__ float lds[4][2048];                 // 8192 B per wave
    const int wave = threadIdx.x >> 6;
    const int lane = threadIdx.x & 63;
    float* wbase = lds[wave];
    char* abufA = (char*)wbase;                    // [16][128] bf16, swizzled
    char* abufB = (char*)wbase + 4096;
    float* combA = wbase;                          // overlap (dead after tfrag)
    float* combB = wbase + 82;
    int bA = blockIdx.x * 8 + wave * 2;
    int bB = bA + 1;
    if (bA >= nb) bA = nb - 1;
    if (bB >= nb) bB = nb - 1;

    // ---------------- layer 0 (4 -> 128), fp32, lane owns cols 2l,2l+1 ------
    {
        const int j0 = lane * 2;
        float w0d[4][2];
        #pragma unroll
        for (int d = 0; d < 4; ++d) {
            float2 w = *reinterpret_cast<const float2*>(W0 + d * HID + j0);
            w0d[d][0] = w.x; w0d[d][1] = w.y;
        }
        const float2 bb0 = *reinterpret_cast<const float2*>(b0 + j0);
        const float4 xvA = *reinterpret_cast<const float4*>(x + 4 * bA);
        const float4 xvB = *reinterpret_cast<const float4*>(x + 4 * bB);
        #pragma unroll
        for (int s = 0; s < 2; ++s) {
            const float4 xv = s ? xvB : xvA;
            char* abuf = s ? abufB : abufA;
            float val[15][2];
            #pragma unroll
            for (int jj = 0; jj < 2; ++jj) {
                float z = ((jj == 0) ? bb0.x : bb0.y)
                        + xv.x * w0d[0][jj] + xv.y * w0d[1][jj]
                        + xv.z * w0d[2][jj] + xv.w * w0d[3][jj];
                float h = tanh_fast(z);
                float sd = 1.f - h * h;
                val[0][jj] = h;
                #pragma unroll
                for (int d = 0; d < 4; ++d) val[1 + d][jj] = sd * w0d[d][jj];
                #pragma unroll
                for (int p = 0; p < 10; ++p)
                    val[5 + p][jj] = -2.f * h * sd * w0d[PD[p]][jj] * w0d[PE[p]][jj];
            }
            #pragma unroll
            for (int v = 0; v < 15; ++v)
                *reinterpret_cast<u32a*>(abuf + swz(ROWMAP[v], j0 * 2)) =
                    pk_bf16(val[v][0], val[v][1]);
            *reinterpret_cast<u32a*>(abuf + swz(4, j0 * 2)) = 0u;   // pad row
        }
    }
    LDS_FENCE();   // layer-0 stores -> afrag reads

    // ---------------- layers 1,2 via 32x32x16 MFMA (stacked samples) --------
    const int col  = lane & 31;                    // output column in tile
    const int hi   = lane >> 5;                    // lane half
    const int arow = lane & 15;                    // A-row within sample
    char* abufM = (char*)wbase + ((lane >> 4) & 1) * 4096;  // m>=16 -> sample B

    #pragma unroll 1
    for (int layer = 0; layer < 2; ++layer) {
        // A fragments: lane holds A[m=lane&31][k = kt*16 + hi*8 + 0..7]
        bf16x8 af[8];
        #pragma unroll
        for (int kt = 0; kt < 8; ++kt)
            af[kt] = *reinterpret_cast<const bf16x8*>(
                abufM + swz(arow, kt * 32 + hi * 16));
        LDS_FENCE();   // afrag reads -> recomb stores (WAR)
        const float* bias = layer ? b2 : b1;
        float bv[4];
        #pragma unroll
        for (int t4 = 0; t4 < 4; ++t4) bv[t4] = bias[t4 * 32 + col];

        #pragma unroll 2
        for (int t4 = 0; t4 < 4; ++t4) {
            f32x16 acc = {0.f,0.f,0.f,0.f,0.f,0.f,0.f,0.f,
                          0.f,0.f,0.f,0.f,0.f,0.f,0.f,0.f};
            #pragma unroll
            for (int kt = 0; kt < 8; ++kt) {
                bf16x8 bfrag = *reinterpret_cast<const bf16x8*>(
                    wsB + ((size_t)(((layer * 8 + kt) * 4) + t4) * 512 + lane * 8));
                acc = __builtin_amdgcn_mfma_f32_32x32x16_bf16(af[kt], bfrag, acc, 0, 0, 0);
            }
            const bool H = (hi != 0);
            // partner-half values via VALU permlane32_swap (no LDS round-trip)
            float swA0 = swap_half(acc[0],  H);
            float swA1 = swap_half(acc[1],  H);
            float swA2 = swap_half(acc[2],  H);
            float swB0 = swap_half(acc[8],  H);
            float swB1 = swap_half(acc[9],  H);
            float swB2 = swap_half(acc[10], H);
            float zA  = H ? swA0   : acc[0];
            float uA0 = H ? swA1   : acc[1];
            float uA1 = H ? acc[1] : swA1;
            float uA2 = H ? swA2   : acc[2];
            float uA3 = H ? acc[2] : swA2;
            float zB  = H ? swB0   : acc[8];
            float uB0 = H ? swB1   : acc[9];
            float uB1 = H ? acc[9] : swB1;
            float uB2 = H ? swB2   : acc[10];
            float uB3 = H ? acc[10] : swB2;
            float hA = tanh_fast(zA + bv[t4]);
            float sA = 1.f - hA * hA;  float cA = -2.f * hA * sA;
            float hB = tanh_fast(zB + bv[t4]);
            float sB = 1.f - hB * hB;  float cB = -2.f * hB * sB;

            float nvA[8], nvB[8];
            nvA[0] = H ? 0.f : hA;                              // rows 0/4: v0|pad
            nvA[1] = sA * (H ? uA1 : uA0);                      // rows 1/5: v1|v2
            nvA[2] = sA * (H ? uA3 : uA2);                      // rows 2/6: v3|v4
            nvA[3] = fmaf(cA * uA0, H ? uA1 : uA0, sA * acc[3]);    // v5|v6
            nvA[4] = fmaf(cA * uA0, H ? uA3 : uA2, sA * acc[4]);    // v7|v8
            nvA[5] = fmaf(cA * uA1, H ? uA2 : uA1, sA * acc[5]);    // v9|v10
            nvA[6] = fmaf(cA * (H ? uA2 : uA1), H ? uA2 : uA3, sA * acc[6]); // v11|v12
            nvA[7] = fmaf(cA * (H ? uA3 : uA2), uA3, sA * acc[7]);  // v13|v14
            nvB[0] = H ? 0.f : hB;
            nvB[1] = sB * (H ? uB1 : uB0);
            nvB[2] = sB * (H ? uB3 : uB2);
            nvB[3] = fmaf(cB * uB0, H ? uB1 : uB0, sB * acc[11]);
            nvB[4] = fmaf(cB * uB0, H ? uB3 : uB2, sB * acc[12]);
            nvB[5] = fmaf(cB * uB1, H ? uB2 : uB1, sB * acc[13]);
            nvB[6] = fmaf(cB * (H ? uB2 : uB1), H ? uB2 : uB3, sB * acc[14]);
            nvB[7] = fmaf(cB * (H ? uB3 : uB2), uB3, sB * acc[15]);

            const int cb = (t4 * 32 + col) * 2;
            #pragma unroll
            for (int q = 0; q < 8; ++q) {
                int rowq = RB[q] + 4 * hi;
                *reinterpret_cast<u16a*>(abufA + swz(rowq, cb)) = bf1(nvA[q]);
                *reinterpret_cast<u16a*>(abufB + swz(rowq, cb)) = bf1(nvB[q]);
            }
        }
        LDS_FENCE();   // recomb stores -> next-layer / epilogue reads
    }

    // ---------------- epilogue: stacked T @ W3pad(128x32) via MFMA ----------
    bf16x8 tf[8];
    #pragma unroll
    for (int kt = 0; kt < 8; ++kt)
        tf[kt] = *reinterpret_cast<const bf16x8*>(
            abufM + swz(arow, kt * 32 + hi * 16));
    LDS_FENCE();   // tfrag reads -> comb stores (comb overlaps abufA)

    f32x16 fa = {0.f,0.f,0.f,0.f,0.f,0.f,0.f,0.f,
                 0.f,0.f,0.f,0.f,0.f,0.f,0.f,0.f};
    #pragma unroll
    for (int kt = 0; kt < 8; ++kt) {
        bf16x8 w3f = *reinterpret_cast<const bf16x8*>(
            wsB + 32768 + (size_t)(kt * 512 + lane * 8));
        fa = __builtin_amdgcn_mfma_f32_32x32x16_bf16(tf[kt], w3f, fa, 0, 0, 0);
    }

    if (col < 5) {
        float badd = (hi != 0) ? 0.f : b3[col];
        #pragma unroll
        for (int q = 0; q < 8; ++q) {
            int rowq = RB[q] + 4 * hi;
            float tA = fa[q];
            float tB = fa[q + 8];
            if (q == 0) { tA += badd; tB += badd; }
            combA[rowq * 5 + col] = tA;            // comb indexed by permuted row
            combB[rowq * 5 + col] = tB;
        }
    }
    if (lane == 63) { combA[80] = 0.f; combA[81] = 1.f; combB[80] = 0.f; combB[81] = 1.f; }
    LDS_FENCE();   // comb stores -> table reads

    // ---------------- table-driven writer: 38 outputs per sample ------------
    if (lane < 38) {
        OSpec sp = g_ospec[lane];
        float a1v = (combA[sp.a0] + combA[sp.a1] + combA[sp.a2]) * combA[sp.m] * sp.s1;
        float a2v = (combA[sp.b0] + combA[sp.b1] + combA[sp.b2]) * combA[sp.m2] * sp.s2;
        out[sp.base * nb + bA * sp.mul + sp.off] = a1v + a2v;
        float c1v = (combB[sp.a0] + combB[sp.a1] + combB[sp.a2]) * combB[sp.m] * sp.s1;
        float c2v = (combB[sp.b0] + combB[sp.b1] + combB[sp.b2]) * combB[sp.m2] * sp.s2;
        out[sp.base * nb + bB * sp.mul + sp.off] = c1v + c2v;
    }
}

} // namespace

extern "C" void kernel_launch(void* const* d_in, const int* in_sizes, int n_in,
                              void* d_out, int out_size, void* d_ws, size_t ws_size,
                              hipStream_t stream) {
    const float* x  = (const float*)d_in[0];
    const float* W0 = (const float*)d_in[1];
    const float* b0 = (const float*)d_in[2];
    const float* W1 = (const float*)d_in[3];
    const float* b1 = (const float*)d_in[4];
    const float* W2 = (const float*)d_in[5];
    const float* b2 = (const float*)d_in[6];
    const float* W3 = (const float*)d_in[7];
    const float* b3 = (const float*)d_in[8];
    float* out = (float*)d_out;
    unsigned short* wsB = (unsigned short*)d_ws;   // ~72 KB used

    const int nb = in_sizes[0] / 4;                // 32768
    pack_w_kernel<<<144, 256, 0, stream>>>(W1, W2, W3, wsB);
    const int blocks = (nb + 7) / 8;               // 8 samples (4 waves x 2) per block
    mlp_pde_kernel<<<blocks, 256, 0, stream>>>(x, W0, b0, b1, b2, b3, wsB, out, nb);
}

// Round 16
// 74.818 us; speedup vs baseline: 2.3355x; 1.0923x over previous
//
#include <hip/hip_runtime.h>
#include <hip/hip_bf16.h>

// GradientLayer: 4->128->128->128->5 tanh MLP; per-sample Jacobian (5x4) and
// Hessians of outputs 0 and 4, combined into 17 outputs.
// Round 16 (from validated round 15):
//  - t4 loop back to "#pragma unroll 1" (one t4-state live: acc 32 regs),
//    bias loaded in-loop (avoids dynamic-index scratch, rule #20).
//  - 4+4 MFMA chain split (accL kt0-3 / accH kt4-7, one add): halves the
//    dependent-chain latency per t4. Spill-free at unroll-1 (R12's failure
//    was full-unroll x 2 chains = 8 live accumulators).
//  - A/B recomb packed as ext_vector float2 -> v_pk_{mul,fma}_f32 (samples
//    share formulas): halves recomb VALU.
//  Goal: allocation <=~102 unified regs -> 5 waves/SIMD (LDS 5x32KB=160KB
//  fits exactly) without the launch-bounds spill cliff.

namespace {

constexpr int HID = 128;

using bf16x8 = __attribute__((ext_vector_type(8))) short;
using f32x16 = __attribute__((ext_vector_type(16))) float;
using f32x2  = __attribute__((ext_vector_type(2))) float;
typedef unsigned       __attribute__((may_alias)) u32a;
typedef unsigned short __attribute__((may_alias)) u16a;

#define LDS_FENCE() asm volatile("" ::: "memory")

struct OSpec {
    int base, mul, off;
    int a0, a1, a2, m;
    int b0, b1, b2, m2;
    float s1, s2;
};

// comb[] indexed by ROW (permuted): value at row*5+k.
// Row map sigma(v): {0:0,1:1,2:5,3:2,4:6,5:3,6:7,7:8,8:12,9:9,10:13,11:10,
// 12:14,13:11,14:15}. Indices below = sigma(v)*5+k of the validated table.
// comb[80]=0, comb[81]=1.
__constant__ OSpec g_ospec[38] = {
    {0,1,0,   0,80,80,81, 80,80,80,81, 1.f,0.f},   // n
    {1,1,0,   5,80,80,81, 80,80,80,81, 1.f,0.f},   // n_t
    {2,3,0,  25,80,80,81, 80,80,80,81, 1.f,0.f},   // n_grd (v2->row5)
    {2,3,1,  10,80,80,81, 80,80,80,81, 1.f,0.f},   //       (v3->row2)
    {2,3,2,  30,80,80,81, 80,80,80,81, 1.f,0.f},   //       (v4->row6)
    {5,3,0,   1,80,80, 0, 80,80,80,81, 1.f,0.f},   // j = n*v
    {5,3,1,   2,80,80, 0, 80,80,80,81, 1.f,0.f},
    {5,3,2,   3,80,80, 0, 80,80,80,81, 1.f,0.f},
    {8,3,0,  25,10,30, 1, 26,11,31, 0, 1.f,1.f},   // j_div
    {8,3,1,  25,10,30, 2, 27,12,32, 0, 1.f,1.f},
    {8,3,2,  25,10,30, 3, 28,13,33, 0, 1.f,1.f},
    {11,1,0,  4,80,80,81, 80,80,80,81, 1.f,0.f},   // Fi
    {12,3,0, 29,80,80,81, 80,80,80,81, 1.f,0.f},   // Fi_grd
    {12,3,1, 14,80,80,81, 80,80,80,81, 1.f,0.f},
    {12,3,2, 34,80,80,81, 80,80,80,81, 1.f,0.f},
    {15,4,0, 39,44,64,81, 80,80,80,81, 1.f,0.f},   // Fi_lap (HFi p=1,2,3)
    {15,4,1, 49,69,54,81, 80,80,80,81, 1.f,0.f},   //        (p=4,5,6)
    {15,4,2, 69,74,59,81, 80,80,80,81, 1.f,0.f},   //        (p=5,7,8)
    {15,4,3, 54,59,79,81, 80,80,80,81, 1.f,0.f},   //        (p=6,8,9)
    {19,3,0,  1,80,80,81, 80,80,80,81, 1.f,0.f},   // v
    {19,3,1,  2,80,80,81, 80,80,80,81, 1.f,0.f},
    {19,3,2,  3,80,80,81, 80,80,80,81, 1.f,0.f},
    {22,1,0,  5,80,80,81, 80,80,80,81, 1.f,0.f},   // v_t
    {23,3,0,  1,80,80,25, 80,80,80,81, 1.f,0.f},   // v_adv
    {23,3,1,  2,80,80,10, 80,80,80,81, 1.f,0.f},
    {23,3,2,  3,80,80,30, 80,80,80,81, 1.f,0.f},
    {26,1,0, 35,65,55,81, 80,80,80,81, 1.f,0.f},   // v_lap (Hn p=1,5,8)
    {27,3,0, 45,65,50,81, 80,80,80,81, 1.f,0.f},   // v_div_grd (p=4,5,6)
    {27,3,1, 65,70,55,81, 80,80,80,81, 1.f,0.f},   //           (p=5,7,8)
    {27,3,2, 50,55,75,81, 80,80,80,81, 1.f,0.f},   //           (p=6,8,9)
    {30,1,0,  0,80,80,81, 80,80,80,81, 2.f,0.f},   // ro = 2n
    {31,1,0,  5,80,80,81, 80,80,80,81, 2.f,0.f},   // ro_t
    {32,3,0, 25,80,80,81, 80,80,80,81, 2.f,0.f},   // ro_grd
    {32,3,1, 10,80,80,81, 80,80,80,81, 2.f,0.f},
    {32,3,2, 30,80,80,81, 80,80,80,81, 2.f,0.f},
    {35,3,0, 25,10,30, 1, 26,11,31, 0, 2.f,2.f},   // rov_div
    {35,3,1, 25,10,30, 2, 27,12,32, 0, 2.f,2.f},
    {35,3,2, 25,10,30, 3, 28,13,33, 0, 2.f,2.f},
};

__device__ __forceinline__ unsigned short f2bf(float f) {
    union { float f; unsigned u; } v; v.f = f;
    unsigned r = v.u + 0x7FFFu + ((v.u >> 16) & 1u);   // RNE (pack kernel only)
    return (unsigned short)(r >> 16);
}
__device__ __forceinline__ unsigned pk_bf16(float lo, float hi) {
    __bf16 l = (__bf16)lo;
    __bf16 h = (__bf16)hi;
    unsigned short ul, uh;
    __builtin_memcpy(&ul, &l, 2);
    __builtin_memcpy(&uh, &h, 2);
    return (unsigned)ul | ((unsigned)uh << 16);
}
__device__ __forceinline__ unsigned short bf1(float x) {
    __bf16 b = (__bf16)x;
    unsigned short u; __builtin_memcpy(&u, &b, 2); return u;
}
__device__ __forceinline__ float tanh_fast(float z) {
    float e = __builtin_amdgcn_exp2f(z * 2.8853900817779268f);
    return 1.0f - 2.0f * __builtin_amdgcn_rcpf(e + 1.0f);
}
// value of x from partner lane (lane ^ 32), via VALU permlane (no LDS).
__device__ __forceinline__ float swap_half(float x, bool hi_) {
    float a = x, b = x;
    asm volatile("v_permlane32_swap_b32 %0, %1" : "+v"(a), "+v"(b));
    return hi_ ? a : b;
}
// swizzled byte offset inside a per-sample [16][128] bf16 A-buffer
__device__ __forceinline__ int swz(int row, int byte_in_row) {
    return (row * 256 + byte_in_row) ^ ((row & 7) << 4);
}

// ---- pack W1/W2 (+ W3 padded to 32 cols) into 32x32x16 B-fragments ---------
__global__ void pack_w_kernel(const float* __restrict__ W1,
                              const float* __restrict__ W2,
                              const float* __restrict__ W3,
                              unsigned short* __restrict__ wsB) {
    int t = blockIdx.x * 256 + threadIdx.x;        // 0..36863
    if (t < 32768) {
        int reg   = t & 7;
        int lane  = (t >> 3) & 63;
        int tile  = (t >> 9) & 3;
        int kt    = (t >> 11) & 7;
        int layer = (t >> 14) & 1;
        int k = kt * 16 + ((lane >> 5) & 1) * 8 + reg;
        int n = tile * 32 + (lane & 31);
        const float* W = layer ? W2 : W1;
        wsB[t] = f2bf(W[k * HID + n]);
    } else if (t < 36864) {
        int tt = t - 32768;
        int reg  = tt & 7;
        int lane = (tt >> 3) & 63;
        int kt   = (tt >> 9) & 7;
        int k = kt * 16 + ((lane >> 5) & 1) * 8 + reg;
        int n = lane & 31;
        wsB[t] = (n < 5) ? f2bf(W3[k * 5 + n]) : (unsigned short)0;
    }
}

__global__ __launch_bounds__(256, 4) void mlp_pde_kernel(
    const float* __restrict__ x,
    const float* __restrict__ W0, const float* __restrict__ b0,
    const float* __restrict__ b1, const float* __restrict__ b2,
    const float* __restrict__ b3,
    const unsigned short* __restrict__ wsB,
    float* __restrict__ out, int nb)
{
    constexpr int PD[10] = {0,0,0,0,1,1,1,2,2,3};
    constexpr int PE[10] = {0,1,2,3,1,2,3,2,3,3};
    constexpr int ROWMAP[15] = {0,1,5,2,6,3,7,8,12,9,13,10,14,11,15}; // v->row
    constexpr int RB[8] = {0,1,2,3,8,9,10,11};     // reg -> base row (hi=0)

    __shared__ float lds[4][2048];                 // 8192 B per wave
    const int wave = threadIdx.x >> 6;
    const int lane = threadIdx.x & 63;
    float* wbase = lds[wave];
    char* abufA = (char*)wbase;                    // [16][128] bf16, swizzled
    char* abufB = (char*)wbase + 4096;
    float* combA = wbase;                          // overlap (dead after tfrag)
    float* combB = wbase + 82;
    int bA = blockIdx.x * 8 + wave * 2;
    int bB = bA + 1;
    if (bA >= nb) bA = nb - 1;
    if (bB >= nb) bB = nb - 1;

    // ---------------- layer 0 (4 -> 128), fp32, lane owns cols 2l,2l+1 ------
    {
        const int j0 = lane * 2;
        float w0d[4][2];
        #pragma unroll
        for (int d = 0; d < 4; ++d) {
            float2 w = *reinterpret_cast<const float2*>(W0 + d * HID + j0);
            w0d[d][0] = w.x; w0d[d][1] = w.y;
        }
        const float2 bb0 = *reinterpret_cast<const float2*>(b0 + j0);
        const float4 xvA = *reinterpret_cast<const float4*>(x + 4 * bA);
        const float4 xvB = *reinterpret_cast<const float4*>(x + 4 * bB);
        #pragma unroll
        for (int s = 0; s < 2; ++s) {
            const float4 xv = s ? xvB : xvA;
            char* abuf = s ? abufB : abufA;
            float val[15][2];
            #pragma unroll
            for (int jj = 0; jj < 2; ++jj) {
                float z = ((jj == 0) ? bb0.x : bb0.y)
                        + xv.x * w0d[0][jj] + xv.y * w0d[1][jj]
                        + xv.z * w0d[2][jj] + xv.w * w0d[3][jj];
                float h = tanh_fast(z);
                float sd = 1.f - h * h;
                val[0][jj] = h;
                #pragma unroll
                for (int d = 0; d < 4; ++d) val[1 + d][jj] = sd * w0d[d][jj];
                #pragma unroll
                for (int p = 0; p < 10; ++p)
                    val[5 + p][jj] = -2.f * h * sd * w0d[PD[p]][jj] * w0d[PE[p]][jj];
            }
            #pragma unroll
            for (int v = 0; v < 15; ++v)
                *reinterpret_cast<u32a*>(abuf + swz(ROWMAP[v], j0 * 2)) =
                    pk_bf16(val[v][0], val[v][1]);
            *reinterpret_cast<u32a*>(abuf + swz(4, j0 * 2)) = 0u;   // pad row
        }
    }
    LDS_FENCE();   // layer-0 stores -> afrag reads

    // ---------------- layers 1,2 via 32x32x16 MFMA (stacked samples) --------
    const int col  = lane & 31;                    // output column in tile
    const int hi   = lane >> 5;                    // lane half
    const int arow = lane & 15;                    // A-row within sample
    char* abufM = (char*)wbase + ((lane >> 4) & 1) * 4096;  // m>=16 -> sample B

    #pragma unroll 1
    for (int layer = 0; layer < 2; ++layer) {
        // A fragments: lane holds A[m=lane&31][k = kt*16 + hi*8 + 0..7]
        bf16x8 af[8];
        #pragma unroll
        for (int kt = 0; kt < 8; ++kt)
            af[kt] = *reinterpret_cast<const bf16x8*>(
                abufM + swz(arow, kt * 32 + hi * 16));
        LDS_FENCE();   // afrag reads -> recomb stores (WAR)
        const float* bias = layer ? b2 : b1;

        #pragma unroll 1
        for (int t4 = 0; t4 < 4; ++t4) {
            const float bvt = bias[t4 * 32 + col];  // L1-hot, in-loop (rule #20)
            // two independent 4-deep chains: halves dependent-MFMA latency
            f32x16 accL = {0.f,0.f,0.f,0.f,0.f,0.f,0.f,0.f,
                           0.f,0.f,0.f,0.f,0.f,0.f,0.f,0.f};
            f32x16 accH = {0.f,0.f,0.f,0.f,0.f,0.f,0.f,0.f,
                           0.f,0.f,0.f,0.f,0.f,0.f,0.f,0.f};
            #pragma unroll
            for (int kt = 0; kt < 4; ++kt) {
                bf16x8 bfL = *reinterpret_cast<const bf16x8*>(
                    wsB + ((size_t)(((layer * 8 + kt) * 4) + t4) * 512 + lane * 8));
                bf16x8 bfH = *reinterpret_cast<const bf16x8*>(
                    wsB + ((size_t)(((layer * 8 + kt + 4) * 4) + t4) * 512 + lane * 8));
                accL = __builtin_amdgcn_mfma_f32_32x32x16_bf16(af[kt],     bfL, accL, 0, 0, 0);
                accH = __builtin_amdgcn_mfma_f32_32x32x16_bf16(af[kt + 4], bfH, accH, 0, 0, 0);
            }
            f32x16 acc = accL + accH;

            const bool H = (hi != 0);
            // partner-half values via VALU permlane32_swap (no LDS round-trip)
            float swA0 = swap_half(acc[0],  H);
            float swA1 = swap_half(acc[1],  H);
            float swA2 = swap_half(acc[2],  H);
            float swB0 = swap_half(acc[8],  H);
            float swB1 = swap_half(acc[9],  H);
            float swB2 = swap_half(acc[10], H);
            // pack samples A (x) and B (y): identical formulas -> v_pk_* math
            f32x2 z  = {H ? swA0    : acc[0],  H ? swB0    : acc[8]};
            f32x2 u0 = {H ? swA1    : acc[1],  H ? swB1    : acc[9]};
            f32x2 u1 = {H ? acc[1]  : swA1,    H ? acc[9]  : swB1};
            f32x2 u2 = {H ? swA2    : acc[2],  H ? swB2    : acc[10]};
            f32x2 u3 = {H ? acc[2]  : swA2,    H ? acc[10] : swB2};
            f32x2 h2;
            h2.x = tanh_fast(z.x + bvt);
            h2.y = tanh_fast(z.y + bvt);
            f32x2 s2 = 1.f - h2 * h2;
            f32x2 c2 = -2.f * h2 * s2;
            f32x2 a3 = {acc[3], acc[11]};
            f32x2 a4 = {acc[4], acc[12]};
            f32x2 a5 = {acc[5], acc[13]};
            f32x2 a6 = {acc[6], acc[14]};
            f32x2 a7 = {acc[7], acc[15]};

            f32x2 nv2[8];
            nv2[0] = H ? (f32x2){0.f, 0.f} : h2;            // rows 0/4: v0|pad
            nv2[1] = s2 * (H ? u1 : u0);                    // rows 1/5: v1|v2
            nv2[2] = s2 * (H ? u3 : u2);                    // rows 2/6: v3|v4
            nv2[3] = c2 * u0 * (H ? u1 : u0) + s2 * a3;     // v5|v6
            nv2[4] = c2 * u0 * (H ? u3 : u2) + s2 * a4;     // v7|v8
            nv2[5] = c2 * u1 * (H ? u2 : u1) + s2 * a5;     // v9|v10
            nv2[6] = c2 * (H ? u2 : u1) * (H ? u2 : u3) + s2 * a6; // v11|v12
            nv2[7] = c2 * (H ? u3 : u2) * u3 + s2 * a7;     // v13|v14

            const int cb = (t4 * 32 + col) * 2;
            #pragma unroll
            for (int q = 0; q < 8; ++q) {
                int rowq = RB[q] + 4 * hi;
                *reinterpret_cast<u16a*>(abufA + swz(rowq, cb)) = bf1(nv2[q].x);
                *reinterpret_cast<u16a*>(abufB + swz(rowq, cb)) = bf1(nv2[q].y);
            }
        }
        LDS_FENCE();   // recomb stores -> next-layer / epilogue reads
    }

    // ---------------- epilogue: stacked T @ W3pad(128x32) via MFMA ----------
    bf16x8 tf[8];
    #pragma unroll
    for (int kt = 0; kt < 8; ++kt)
        tf[kt] = *reinterpret_cast<const bf16x8*>(
            abufM + swz(arow, kt * 32 + hi * 16));
    LDS_FENCE();   // tfrag reads -> comb stores (comb overlaps abufA)

    f32x16 fa = {0.f,0.f,0.f,0.f,0.f,0.f,0.f,0.f,
                 0.f,0.f,0.f,0.f,0.f,0.f,0.f,0.f};
    #pragma unroll
    for (int kt = 0; kt < 8; ++kt) {
        bf16x8 w3f = *reinterpret_cast<const bf16x8*>(
            wsB + 32768 + (size_t)(kt * 512 + lane * 8));
        fa = __builtin_amdgcn_mfma_f32_32x32x16_bf16(tf[kt], w3f, fa, 0, 0, 0);
    }

    if (col < 5) {
        float badd = (hi != 0) ? 0.f : b3[col];
        #pragma unroll
        for (int q = 0; q < 8; ++q) {
            int rowq = RB[q] + 4 * hi;
            float tA = fa[q];
            float tB = fa[q + 8];
            if (q == 0) { tA += badd; tB += badd; }
            combA[rowq * 5 + col] = tA;            // comb indexed by permuted row
            combB[rowq * 5 + col] = tB;
        }
    }
    if (lane == 63) { combA[80] = 0.f; combA[81] = 1.f; combB[80] = 0.f; combB[81] = 1.f; }
    LDS_FENCE();   // comb stores -> table reads

    // ---------------- table-driven writer: 38 outputs per sample ------------
    if (lane < 38) {
        OSpec sp = g_ospec[lane];
        float a1v = (combA[sp.a0] + combA[sp.a1] + combA[sp.a2]) * combA[sp.m] * sp.s1;
        float a2v = (combA[sp.b0] + combA[sp.b1] + combA[sp.b2]) * combA[sp.m2] * sp.s2;
        out[sp.base * nb + bA * sp.mul + sp.off] = a1v + a2v;
        float c1v = (combB[sp.a0] + combB[sp.a1] + combB[sp.a2]) * combB[sp.m] * sp.s1;
        float c2v = (combB[sp.b0] + combB[sp.b1] + combB[sp.b2]) * combB[sp.m2] * sp.s2;
        out[sp.base * nb + bB * sp.mul + sp.off] = c1v + c2v;
    }
}

} // namespace

extern "C" void kernel_launch(void* const* d_in, const int* in_sizes, int n_in,
                              void* d_out, int out_size, void* d_ws, size_t ws_size,
                              hipStream_t stream) {
    const float* x  = (const float*)d_in[0];
    const float* W0 = (const float*)d_in[1];
    const float* b0 = (const float*)d_in[2];
    const float* W1 = (const float*)d_in[3];
    const float* b1 = (const float*)d_in[4];
    const float* W2 = (const float*)d_in[5];
    const float* b2 = (const float*)d_in[6];
    const float* W3 = (const float*)d_in[7];
    const float* b3 = (const float*)d_in[8];
    float* out = (float*)d_out;
    unsigned short* wsB = (unsigned short*)d_ws;   // ~72 KB used

    const int nb = in_sizes[0] / 4;                // 32768
    pack_w_kernel<<<144, 256, 0, stream>>>(W1, W2, W3, wsB);
    const int blocks = (nb + 7) / 8;               // 8 samples (4 waves x 2) per block
    mlp_pde_kernel<<<blocks, 256, 0, stream>>>(x, W0, b0, b1, b2, b3, wsB, out, nb);
}